// Round 1
// baseline (539.050 us; speedup 1.0000x reference)
//
#include <hip/hip_runtime.h>
#include <hip/hip_bf16.h>
#include <math.h>

#define S_LEN 2048
#define HID   4096
#define NQKV  6144
#define NHEAD 32
#define NKVH  8
#define HDIM  128

typedef __attribute__((ext_vector_type(8))) short short8;
typedef __attribute__((ext_vector_type(4))) float f32x4;

__device__ __forceinline__ unsigned short f2bf(float f) {
    union { float f; unsigned u; } v; v.f = f;
    unsigned r = v.u + 0x7fffu + ((v.u >> 16) & 1u);
    return (unsigned short)(r >> 16);
}

// ---------------- fp32 -> bf16 convert ----------------
__global__ __launch_bounds__(256)
void cvt_kernel(const float* __restrict__ in, unsigned short* __restrict__ out, int n) {
    int idx = (blockIdx.x * 256 + threadIdx.x) * 4;
    int stride = gridDim.x * 256 * 4;
    for (; idx < n; idx += stride) {
        float4 v = *(const float4*)(in + idx);
        ushort4 o;
        o.x = f2bf(v.x); o.y = f2bf(v.y); o.z = f2bf(v.z); o.w = f2bf(v.w);
        *(ushort4*)(out + idx) = o;
    }
}

// ---------------- FWHT over 4096, * su, * 1/4096, -> bf16 ----------------
__global__ __launch_bounds__(256)
void fwht_kernel(const float* __restrict__ in, const float* __restrict__ su,
                 unsigned short* __restrict__ out) {
    __shared__ float buf[HID];
    const float* src = in + (size_t)blockIdx.x * HID;
    for (int i = threadIdx.x; i < HID; i += 256) buf[i] = src[i] * su[i];
    __syncthreads();
    int lg = 0;
    for (int h = 1; h < HID; h <<= 1, ++lg) {
        for (int p = threadIdx.x; p < HID / 2; p += 256) {
            int j  = p & (h - 1);
            int i0 = ((p >> lg) << (lg + 1)) | j;
            int i1 = i0 + h;
            float a = buf[i0], b = buf[i1];
            buf[i0] = a + b;
            buf[i1] = a - b;
        }
        __syncthreads();
    }
    unsigned short* dst = out + (size_t)blockIdx.x * HID;
    const float norm = 1.0f / 4096.0f;   // (1/sqrt(4096)) * (1/SCALE)
    for (int i = threadIdx.x; i < HID; i += 256) dst[i] = f2bf(buf[i] * norm);
}

// ---------------- bf16 GEMM: C[m][n] = (sum_k A[m][k]*B[n][k]) * scale[n] * 64 ----------------
__global__ __launch_bounds__(256)
void gemm_bt(const unsigned short* __restrict__ A, const unsigned short* __restrict__ B,
             const float* __restrict__ scale, float* __restrict__ C,
             int M, int N, int K) {
    __shared__ __attribute__((aligned(16))) unsigned short As[2][128 * 32];
    __shared__ __attribute__((aligned(16))) unsigned short Bs[2][128 * 32];
    const int bn = blockIdx.x, bm = blockIdx.y;
    const int tid = threadIdx.x;
    const int wv = tid >> 6, lane = tid & 63;
    const int wr = wv >> 1, wc = wv & 1;
    const int lr = lane & 15, lgp = lane >> 4;

    f32x4 acc[4][4] = {};

    auto stage = [&](int buf, int kt) {
        for (int c = wv; c < 8; c += 4) {
            int o = c * 512 + lane * 8;
            int row = o >> 5, col = o & 31;
            const unsigned short* ga = A + (size_t)(bm * 128 + row) * K + kt * 32 + col;
            __builtin_amdgcn_global_load_lds((const __attribute__((address_space(1))) void*)ga,
                (__attribute__((address_space(3))) void*)&As[buf][c * 512], 16, 0, 0);
            const unsigned short* gb = B + (size_t)(bn * 128 + row) * K + kt * 32 + col;
            __builtin_amdgcn_global_load_lds((const __attribute__((address_space(1))) void*)gb,
                (__attribute__((address_space(3))) void*)&Bs[buf][c * 512], 16, 0, 0);
        }
    };

    const int nt = K >> 5;
    stage(0, 0);
    __syncthreads();
    int cur = 0;
    for (int kt = 0; kt < nt; ++kt) {
        if (kt + 1 < nt) stage(cur ^ 1, kt + 1);
        const int ko = lgp * 8;
        short8 af[4], bfr[4];
#pragma unroll
        for (int m2 = 0; m2 < 4; ++m2)
            af[m2] = *(const short8*)&As[cur][(wr * 64 + m2 * 16 + lr) * 32 + ko];
#pragma unroll
        for (int n2 = 0; n2 < 4; ++n2)
            bfr[n2] = *(const short8*)&Bs[cur][(wc * 64 + n2 * 16 + lr) * 32 + ko];
#pragma unroll
        for (int m2 = 0; m2 < 4; ++m2)
#pragma unroll
            for (int n2 = 0; n2 < 4; ++n2)
                acc[m2][n2] = __builtin_amdgcn_mfma_f32_16x16x32_bf16(af[m2], bfr[n2], acc[m2][n2], 0, 0, 0);
        __syncthreads();
        cur ^= 1;
    }

#pragma unroll
    for (int n2 = 0; n2 < 4; ++n2) {
        int gn = bn * 128 + wc * 64 + n2 * 16 + lr;
        float sc = scale[gn] * 64.0f;
#pragma unroll
        for (int m2 = 0; m2 < 4; ++m2) {
            int gm0 = bm * 128 + wr * 64 + m2 * 16 + lgp * 4;
#pragma unroll
            for (int i = 0; i < 4; ++i)
                C[(size_t)(gm0 + i) * N + gn] = acc[m2][n2][i] * sc;
        }
    }
}

// ---------------- RoPE + relayout to head-major bf16 Q/K/V ----------------
__global__ __launch_bounds__(256)
void rope_kernel(const float* __restrict__ qkv, const int* __restrict__ pos,
                 unsigned short* __restrict__ Qb, unsigned short* __restrict__ Kb,
                 unsigned short* __restrict__ Vb) {
    const int s = blockIdx.x;
    const float p = (float)pos[s];
    const float* row = qkv + (size_t)s * NQKV;
    for (int idx = threadIdx.x; idx < NQKV; idx += 256) {
        float v = row[idx];
        if (idx < HID + NKVH * HDIM) {      // q or k -> RoPE
            int base = (idx < HID) ? 0 : HID;
            int rel = idx - base;
            int h = rel >> 7, d = rel & 127;
            int j = d & 63;
            float invf = expf((float)j * (-13.122363377404329f / 64.0f)); // theta^(-2j/128)
            float ang = p * invf;
            float sn, cs;
            sincosf(ang, &sn, &cs);
            float other = (d < 64) ? -row[base + h * 128 + d + 64]
                                   :  row[base + h * 128 + d - 64];
            unsigned short ob = f2bf(v * cs + other * sn);
            if (idx < HID) Qb[((size_t)h * S_LEN + s) * HDIM + d] = ob;
            else           Kb[((size_t)h * S_LEN + s) * HDIM + d] = ob;
        } else {                             // v passthrough
            int rel = idx - (HID + NKVH * HDIM);
            int h = rel >> 7, d = rel & 127;
            Vb[((size_t)h * S_LEN + s) * HDIM + d] = f2bf(v);
        }
    }
}

// ---------------- causal GQA flash attention ----------------
__global__ __launch_bounds__(256)
void attn_kernel(const unsigned short* __restrict__ Q, const unsigned short* __restrict__ K,
                 const unsigned short* __restrict__ V, float* __restrict__ O) {
    const int qb = blockIdx.x;          // 0..31  (64 q rows each)
    const int h  = blockIdx.y;          // 0..31
    const int kvh = h >> 2;             // GQA group of 4
    const int tid = threadIdx.x, wv = tid >> 6, lane = tid & 63;
    const int lr = lane & 15, lgp = lane >> 4;

    __shared__ __attribute__((aligned(16))) unsigned short Ks[64 * 128];
    __shared__ __attribute__((aligned(16))) unsigned short Vt[128 * 64];
    __shared__ __attribute__((aligned(16))) unsigned short Ps[4][16 * 64];

    const int qrow = qb * 64 + wv * 16 + lr;
    short8 aq[4];
    {
        const unsigned short* qp = Q + ((size_t)h * S_LEN + qrow) * HDIM + lgp * 8;
#pragma unroll
        for (int kk = 0; kk < 4; ++kk) aq[kk] = *(const short8*)(qp + kk * 32);
    }

    f32x4 oacc[8] = {};
    float m_i[4], l_i[4];
#pragma unroll
    for (int i = 0; i < 4; ++i) { m_i[i] = -3.0e38f; l_i[i] = 0.f; }

    const float sm = 0.08838834764831845f;  // 1/sqrt(128)

    for (int kb = 0; kb <= qb; ++kb) {
        __syncthreads();
        {
            const unsigned short* kg = K + ((size_t)kvh * S_LEN + kb * 64) * HDIM;
            const unsigned short* vg = V + ((size_t)kvh * S_LEN + kb * 64) * HDIM;
#pragma unroll
            for (int r2 = 0; r2 < 4; ++r2) {
                // K tile: contiguous read, swizzled row-major [64][128] store
                int o = (tid + r2 * 256) * 8;
                int krow = o >> 7;
                *(short8*)&Ks[o ^ ((krow & 7) << 3)] = *(const short8*)(kg + o);
                // V tile: gather read (kv = lane), conflict-free transposed store [128][64]
                int d0 = wv * 32 + r2 * 8;
                short8 vvec = *(const short8*)(vg + lane * 128 + d0);
#pragma unroll
                for (int e = 0; e < 8; ++e) {
                    int d = d0 + e;
                    Vt[(d * 64 + lane) ^ ((d & 7) << 3)] = ((const unsigned short*)&vvec)[e];
                }
            }
        }
        __syncthreads();

        // QK^T : S[16 q][64 kv]
        f32x4 sc[4];
#pragma unroll
        for (int nt2 = 0; nt2 < 4; ++nt2) {
            f32x4 a = {};
            int krow = nt2 * 16 + lr;
#pragma unroll
            for (int kk = 0; kk < 4; ++kk) {
                short8 bk = *(const short8*)&Ks[(krow * 128 + kk * 32 + lgp * 8) ^ ((krow & 7) << 3)];
                a = __builtin_amdgcn_mfma_f32_16x16x32_bf16(aq[kk], bk, a, 0, 0, 0);
            }
            sc[nt2] = a;
        }

        if (kb == qb) {
#pragma unroll
            for (int nt2 = 0; nt2 < 4; ++nt2) {
                int colg = nt2 * 16 + lr;
#pragma unroll
                for (int i = 0; i < 4; ++i) {
                    int rowg = wv * 16 + lgp * 4 + i;
                    sc[nt2][i] = (colg > rowg) ? -1.0e30f : sc[nt2][i] * sm;
                }
            }
        } else {
#pragma unroll
            for (int nt2 = 0; nt2 < 4; ++nt2)
#pragma unroll
                for (int i = 0; i < 4; ++i) sc[nt2][i] *= sm;
        }

        // online softmax (per q-row i; row spread over 16 lanes lr)
        float fesc[4];
#pragma unroll
        for (int i = 0; i < 4; ++i) {
            float v = fmaxf(fmaxf(sc[0][i], sc[1][i]), fmaxf(sc[2][i], sc[3][i]));
            v = fmaxf(v, __shfl_xor(v, 1));
            v = fmaxf(v, __shfl_xor(v, 2));
            v = fmaxf(v, __shfl_xor(v, 4));
            v = fmaxf(v, __shfl_xor(v, 8));
            float mn = fmaxf(m_i[i], v);
            fesc[i] = __expf(m_i[i] - mn);
            m_i[i] = mn;
            l_i[i] *= fesc[i];
        }
#pragma unroll
        for (int t = 0; t < 8; ++t)
#pragma unroll
            for (int i = 0; i < 4; ++i) oacc[t][i] *= fesc[i];

        float rs[4] = {0.f, 0.f, 0.f, 0.f};
#pragma unroll
        for (int nt2 = 0; nt2 < 4; ++nt2)
#pragma unroll
            for (int i = 0; i < 4; ++i) {
                float pv = __expf(sc[nt2][i] - m_i[i]);
                sc[nt2][i] = pv;
                rs[i] += pv;
            }
#pragma unroll
        for (int i = 0; i < 4; ++i) {
            float v = rs[i];
            v += __shfl_xor(v, 1);
            v += __shfl_xor(v, 2);
            v += __shfl_xor(v, 4);
            v += __shfl_xor(v, 8);
            l_i[i] += v;
        }

        // P: D-layout -> (LDS, swizzled) -> A-layout bf16
        unsigned short* pw = &Ps[wv][0];
#pragma unroll
        for (int nt2 = 0; nt2 < 4; ++nt2)
#pragma unroll
            for (int i = 0; i < 4; ++i) {
                int r = lgp * 4 + i;
                pw[(r * 64 + nt2 * 16 + lr) ^ ((r & 7) << 3)] = f2bf(sc[nt2][i]);
            }
        short8 ap[2];
#pragma unroll
        for (int kk = 0; kk < 2; ++kk)
            ap[kk] = *(const short8*)&pw[(lr * 64 + kk * 32 + lgp * 8) ^ ((lr & 7) << 3)];

        // PV
#pragma unroll
        for (int t = 0; t < 8; ++t)
#pragma unroll
            for (int kk = 0; kk < 2; ++kk) {
                int vrow = t * 16 + lr;
                short8 bv = *(const short8*)&Vt[(vrow * 64 + kk * 32 + lgp * 8) ^ ((vrow & 7) << 3)];
                oacc[t] = __builtin_amdgcn_mfma_f32_16x16x32_bf16(ap[kk], bv, oacc[t], 0, 0, 0);
            }
    }

    float invl[4];
#pragma unroll
    for (int i = 0; i < 4; ++i) invl[i] = 1.0f / l_i[i];
    const int row0 = qb * 64 + wv * 16 + lgp * 4;
    float* ob = O + (size_t)row0 * HID + h * HDIM;
#pragma unroll
    for (int t = 0; t < 8; ++t)
#pragma unroll
        for (int i = 0; i < 4; ++i)
            ob[(size_t)i * HID + t * 16 + lr] = oacc[t][i] * invl[i];
}

// ---------------- launch ----------------
extern "C" void kernel_launch(void* const* d_in, const int* in_sizes, int n_in,
                              void* d_out, int out_size, void* d_ws, size_t ws_size,
                              hipStream_t stream) {
    const float* hidden = (const float*)d_in[0];
    const int*   pos    = (const int*)d_in[1];
    const float* su_qkv = (const float*)d_in[2];
    const float* su_o   = (const float*)d_in[3];
    const float* ws_qkv = (const float*)d_in[4];
    const float* ws_o   = (const float*)d_in[5];
    const float* Wq     = (const float*)d_in[6];
    const float* Wk     = (const float*)d_in[7];
    const float* Wv     = (const float*)d_in[8];
    const float* Wo     = (const float*)d_in[9];
    float* out = (float*)d_out;

    char* ws = (char*)d_ws;
    unsigned short* Wcat = (unsigned short*)(ws);                        // [6144][4096] bf16
    unsigned short* Wob  = (unsigned short*)(ws + 50331648);             // [4096][4096] bf16
    unsigned short* xb   = (unsigned short*)(ws + 83886080);             // [2048][4096] bf16 (reused as y_in)
    float*          qkv  = (float*)(ws + 100663296);                     // [2048][6144] f32 (reused as attn_out)
    unsigned short* Qb   = (unsigned short*)(ws + 150994944);            // [32][2048][128] bf16
    unsigned short* Kb   = Qb + (size_t)NHEAD * S_LEN * HDIM;
    unsigned short* Vb   = Kb + (size_t)NKVH * S_LEN * HDIM;
    float* attn_out = qkv;

    cvt_kernel<<<1024, 256, 0, stream>>>(Wq, Wcat, HID * HID);
    cvt_kernel<<<256, 256, 0, stream>>>(Wk, Wcat + (size_t)HID * HID, NKVH * HDIM * HID);
    cvt_kernel<<<256, 256, 0, stream>>>(Wv, Wcat + (size_t)(HID + NKVH * HDIM) * HID, NKVH * HDIM * HID);
    cvt_kernel<<<1024, 256, 0, stream>>>(Wo, Wob, HID * HID);

    fwht_kernel<<<S_LEN, 256, 0, stream>>>(hidden, su_qkv, xb);
    gemm_bt<<<dim3(NQKV / 128, S_LEN / 128), 256, 0, stream>>>(xb, Wcat, ws_qkv, qkv, S_LEN, NQKV, HID);
    rope_kernel<<<S_LEN, 256, 0, stream>>>(qkv, pos, Qb, Kb, Vb);
    attn_kernel<<<dim3(S_LEN / 64, NHEAD), 256, 0, stream>>>(Qb, Kb, Vb, attn_out);
    fwht_kernel<<<S_LEN, 256, 0, stream>>>(attn_out, su_o, xb);
    gemm_bt<<<dim3(HID / 128, S_LEN / 128), 256, 0, stream>>>(xb, Wob, ws_o, out, S_LEN, HID, HID);
}

// Round 2
// 496.019 us; speedup vs baseline: 1.0868x; 1.0868x over previous
//
#include <hip/hip_runtime.h>
#include <hip/hip_bf16.h>
#include <math.h>

#define S_LEN 2048
#define HID   4096
#define NQKV  6144
#define NHEAD 32
#define NKVH  8
#define HDIM  128

typedef __attribute__((ext_vector_type(8))) short short8;
typedef __attribute__((ext_vector_type(4))) short short4v;
typedef __attribute__((ext_vector_type(4))) float f32x4;

__device__ __forceinline__ unsigned short f2bf(float f) {
    union { float f; unsigned u; } v; v.f = f;
    unsigned r = v.u + 0x7fffu + ((v.u >> 16) & 1u);
    return (unsigned short)(r >> 16);
}

// ---------------- fp32 -> bf16 convert ----------------
__global__ __launch_bounds__(256)
void cvt_kernel(const float* __restrict__ in, unsigned short* __restrict__ out, int n) {
    int idx = (blockIdx.x * 256 + threadIdx.x) * 4;
    int stride = gridDim.x * 256 * 4;
    for (; idx < n; idx += stride) {
        float4 v = *(const float4*)(in + idx);
        ushort4 o;
        o.x = f2bf(v.x); o.y = f2bf(v.y); o.z = f2bf(v.z); o.w = f2bf(v.w);
        *(ushort4*)(out + idx) = o;
    }
}

// ---------------- FWHT over 4096, * su, * 1/4096, -> bf16 ----------------
__global__ __launch_bounds__(256)
void fwht_kernel(const float* __restrict__ in, const float* __restrict__ su,
                 unsigned short* __restrict__ out) {
    __shared__ float buf[HID];
    const float* src = in + (size_t)blockIdx.x * HID;
    for (int i = threadIdx.x; i < HID; i += 256) buf[i] = src[i] * su[i];
    __syncthreads();
    int lg = 0;
    for (int h = 1; h < HID; h <<= 1, ++lg) {
        for (int p = threadIdx.x; p < HID / 2; p += 256) {
            int j  = p & (h - 1);
            int i0 = ((p >> lg) << (lg + 1)) | j;
            int i1 = i0 + h;
            float a = buf[i0], b = buf[i1];
            buf[i0] = a + b;
            buf[i1] = a - b;
        }
        __syncthreads();
    }
    unsigned short* dst = out + (size_t)blockIdx.x * HID;
    const float norm = 1.0f / 4096.0f;   // (1/sqrt(4096)) * (1/SCALE)
    for (int i = threadIdx.x; i < HID; i += 256) dst[i] = f2bf(buf[i] * norm);
}

// ---------------- bf16 GEMM: C[m][n] = (sum_k A[m][k]*B[n][k]) * scale[n] * 64 ----------------
__global__ __launch_bounds__(256)
void gemm_bt(const unsigned short* __restrict__ A, const unsigned short* __restrict__ B,
             const float* __restrict__ scale, float* __restrict__ C,
             int M, int N, int K) {
    __shared__ __attribute__((aligned(16))) unsigned short As[2][128 * 32];
    __shared__ __attribute__((aligned(16))) unsigned short Bs[2][128 * 32];
    const int bn = blockIdx.x, bm = blockIdx.y;
    const int tid = threadIdx.x;
    const int wv = tid >> 6, lane = tid & 63;
    const int wr = wv >> 1, wc = wv & 1;
    const int lr = lane & 15, lgp = lane >> 4;

    f32x4 acc[4][4] = {};

    auto stage = [&](int buf, int kt) {
        for (int c = wv; c < 8; c += 4) {
            int o = c * 512 + lane * 8;
            int row = o >> 5, col = o & 31;
            const unsigned short* ga = A + (size_t)(bm * 128 + row) * K + kt * 32 + col;
            __builtin_amdgcn_global_load_lds((const __attribute__((address_space(1))) void*)ga,
                (__attribute__((address_space(3))) void*)&As[buf][c * 512], 16, 0, 0);
            const unsigned short* gb = B + (size_t)(bn * 128 + row) * K + kt * 32 + col;
            __builtin_amdgcn_global_load_lds((const __attribute__((address_space(1))) void*)gb,
                (__attribute__((address_space(3))) void*)&Bs[buf][c * 512], 16, 0, 0);
        }
    };

    const int nt = K >> 5;
    stage(0, 0);
    __syncthreads();
    int cur = 0;
    for (int kt = 0; kt < nt; ++kt) {
        if (kt + 1 < nt) stage(cur ^ 1, kt + 1);
        const int ko = lgp * 8;
        short8 af[4], bfr[4];
#pragma unroll
        for (int m2 = 0; m2 < 4; ++m2)
            af[m2] = *(const short8*)&As[cur][(wr * 64 + m2 * 16 + lr) * 32 + ko];
#pragma unroll
        for (int n2 = 0; n2 < 4; ++n2)
            bfr[n2] = *(const short8*)&Bs[cur][(wc * 64 + n2 * 16 + lr) * 32 + ko];
#pragma unroll
        for (int m2 = 0; m2 < 4; ++m2)
#pragma unroll
            for (int n2 = 0; n2 < 4; ++n2)
                acc[m2][n2] = __builtin_amdgcn_mfma_f32_16x16x32_bf16(af[m2], bfr[n2], acc[m2][n2], 0, 0, 0);
        __syncthreads();
        cur ^= 1;
    }

#pragma unroll
    for (int n2 = 0; n2 < 4; ++n2) {
        int gn = bn * 128 + wc * 64 + n2 * 16 + lr;
        float sc = scale[gn] * 64.0f;
#pragma unroll
        for (int m2 = 0; m2 < 4; ++m2) {
            int gm0 = bm * 128 + wr * 64 + m2 * 16 + lgp * 4;
#pragma unroll
            for (int i = 0; i < 4; ++i)
                C[(size_t)(gm0 + i) * N + gn] = acc[m2][n2][i] * sc;
        }
    }
}

// ---------------- RoPE + relayout to head-major bf16 Q/K/V ----------------
__global__ __launch_bounds__(256)
void rope_kernel(const float* __restrict__ qkv, const int* __restrict__ pos,
                 unsigned short* __restrict__ Qb, unsigned short* __restrict__ Kb,
                 unsigned short* __restrict__ Vb) {
    const int s = blockIdx.x;
    const float p = (float)pos[s];
    const float* row = qkv + (size_t)s * NQKV;
    for (int idx = threadIdx.x; idx < NQKV; idx += 256) {
        float v = row[idx];
        if (idx < HID + NKVH * HDIM) {      // q or k -> RoPE
            int base = (idx < HID) ? 0 : HID;
            int rel = idx - base;
            int h = rel >> 7, d = rel & 127;
            int j = d & 63;
            float invf = expf((float)j * (-13.122363377404329f / 64.0f)); // theta^(-2j/128)
            float ang = p * invf;
            float sn, cs;
            sincosf(ang, &sn, &cs);
            float other = (d < 64) ? -row[base + h * 128 + d + 64]
                                   :  row[base + h * 128 + d - 64];
            unsigned short ob = f2bf(v * cs + other * sn);
            if (idx < HID) Qb[((size_t)h * S_LEN + s) * HDIM + d] = ob;
            else           Kb[((size_t)h * S_LEN + s) * HDIM + d] = ob;
        } else {                             // v passthrough
            int rel = idx - (HID + NKVH * HDIM);
            int h = rel >> 7, d = rel & 127;
            Vb[((size_t)h * S_LEN + s) * HDIM + d] = f2bf(v);
        }
    }
}

// ---------------- causal GQA flash attention (swapped QK^T, in-reg softmax) ----------------
// grid (16, 32): block x handles q-tiles x and 31-x (balanced: 33 kv-iters each).
// Per 64-row q-tile: 4 waves x 16 q-rows. Swapped QK^T (K as A-operand) puts
// scores S^T in regs: lane (16g+r) holds S[kv=nt2*16+4g+i][q=r] -> softmax is
// in-register + 4 shfl_xor; P feeds PV's A-operand directly (permuted-k
// convention matched by the V^T fragment reads).
__global__ __launch_bounds__(256)
void attn_kernel(const unsigned short* __restrict__ Q, const unsigned short* __restrict__ K,
                 const unsigned short* __restrict__ V, float* __restrict__ O) {
    const int h  = blockIdx.y;
    const int kvh = h >> 2;
    const int tid = threadIdx.x, wv = tid >> 6, lane = tid & 63;
    const int lr = lane & 15, lgp = lane >> 4;

    __shared__ __attribute__((aligned(16))) unsigned short Ks[2][64 * 128];
    __shared__ __attribute__((aligned(16))) unsigned short Vt[2][128 * 64];

    // per-thread pre-swizzled K staging source offsets (global_load_lds: linear
    // LDS dest, swizzled global source -> swizzled row-major [64][128] K tile)
    int koff[4];
#pragma unroll
    for (int j = 0; j < 4; ++j) {
        int a = (wv * 4 + j) * 512 + lane * 8;
        koff[j] = a ^ (((a >> 7) & 7) << 3);
    }
    const unsigned short* Kg = K + (size_t)kvh * S_LEN * HDIM;
    const unsigned short* Vg = V + (size_t)kvh * S_LEN * HDIM;
    const float sm = 0.08838834764831845f;  // 1/sqrt(128)

    auto stageK = [&](int buf, int kb) {
        const unsigned short* kg = Kg + (size_t)kb * 64 * HDIM;
#pragma unroll
        for (int j = 0; j < 4; ++j) {
            __builtin_amdgcn_global_load_lds(
                (const __attribute__((address_space(1))) void*)(kg + koff[j]),
                (__attribute__((address_space(3))) void*)&Ks[buf][(wv * 4 + j) * 512], 16, 0, 0);
        }
    };

#pragma unroll 1
    for (int rep = 0; rep < 2; ++rep) {
        const int qt = rep ? (31 - (int)blockIdx.x) : (int)blockIdx.x;
        const int qg = qt * 64 + wv * 16 + lr;   // this lane's q row (column of S^T)

        __syncthreads();   // LDS reuse guard across reps

        short8 aq[4];
        {
            const unsigned short* qp = Q + ((size_t)h * S_LEN + qg) * HDIM + lgp * 8;
#pragma unroll
            for (int kk = 0; kk < 4; ++kk) aq[kk] = *(const short8*)(qp + kk * 32);
        }

        f32x4 oacc[8] = {};
        float m_i = -3.0e38f, l_i = 0.f;

        // prologue: stage K(0), prefetch V(0) into regs
        short8 vcur[4], vnext[4];
        stageK(0, 0);
        {
            const unsigned short* vp = Vg + lane * HDIM + wv * 32;
#pragma unroll
            for (int r2 = 0; r2 < 4; ++r2) vcur[r2] = *(const short8*)(vp + r2 * 8);
        }

        int cur = 0;
#pragma unroll 1
        for (int kb = 0; kb <= qt; ++kb) {
            // scatter V regs -> transposed swizzled Vt[cur]  ([d][kv], ^((d&7)<<3))
#pragma unroll
            for (int r2 = 0; r2 < 4; ++r2) {
#pragma unroll
                for (int e = 0; e < 8; ++e) {
                    int d = wv * 32 + r2 * 8 + e;
                    Vt[cur][(d * 64 + lane) ^ ((d & 7) << 3)] = ((const unsigned short*)&vcur[r2])[e];
                }
            }
            __syncthreads();   // drains prev K gload_lds (vmcnt) + scatter (lgkm) + barrier

            if (kb < qt) {     // issue NEXT tile's loads; they fly during compute
                stageK(cur ^ 1, kb + 1);
                const unsigned short* vp = Vg + (size_t)(kb + 1) * 64 * HDIM + lane * HDIM + wv * 32;
#pragma unroll
                for (int r2 = 0; r2 < 4; ++r2) vnext[r2] = *(const short8*)(vp + r2 * 8);
            }

            __builtin_amdgcn_s_setprio(1);
            // QK^T swapped: sc[nt2] rows = kv (nt2*16 + 4*lgp + i), cols = q (lr)
            f32x4 sc[4];
#pragma unroll
            for (int nt2 = 0; nt2 < 4; ++nt2) {
                f32x4 a = {};
                const int krow = nt2 * 16 + lr;
                const int swz = (krow & 7) << 3;
#pragma unroll
                for (int kk = 0; kk < 4; ++kk) {
                    short8 ak = *(const short8*)&Ks[cur][(krow * 128 + kk * 32 + lgp * 8) ^ swz];
                    a = __builtin_amdgcn_mfma_f32_16x16x32_bf16(ak, aq[kk], a, 0, 0, 0);
                }
                sc[nt2] = a;
            }
            __builtin_amdgcn_s_setprio(0);

            // scale + causal mask (diag tile only)
            if (kb == qt) {
#pragma unroll
                for (int nt2 = 0; nt2 < 4; ++nt2)
#pragma unroll
                    for (int i = 0; i < 4; ++i) {
                        int kvg = kb * 64 + nt2 * 16 + 4 * lgp + i;
                        sc[nt2][i] = (kvg > qg) ? -1.0e30f : sc[nt2][i] * sm;
                    }
            } else {
#pragma unroll
                for (int nt2 = 0; nt2 < 4; ++nt2)
#pragma unroll
                    for (int i = 0; i < 4; ++i) sc[nt2][i] *= sm;
            }

            // in-register online softmax for q = lr
            float vmax = fmaxf(fmaxf(fmaxf(sc[0][0], sc[0][1]), fmaxf(sc[0][2], sc[0][3])),
                               fmaxf(fmaxf(sc[1][0], sc[1][1]), fmaxf(sc[1][2], sc[1][3])));
            vmax = fmaxf(vmax, fmaxf(fmaxf(fmaxf(sc[2][0], sc[2][1]), fmaxf(sc[2][2], sc[2][3])),
                                     fmaxf(fmaxf(sc[3][0], sc[3][1]), fmaxf(sc[3][2], sc[3][3]))));
            vmax = fmaxf(vmax, __shfl_xor(vmax, 16));
            vmax = fmaxf(vmax, __shfl_xor(vmax, 32));
            float mn = fmaxf(m_i, vmax);
            float fe = __expf(m_i - mn);
            m_i = mn;
            l_i *= fe;
            float rs = 0.f;
#pragma unroll
            for (int nt2 = 0; nt2 < 4; ++nt2)
#pragma unroll
                for (int i = 0; i < 4; ++i) {
                    float pv = __expf(sc[nt2][i] - mn);
                    sc[nt2][i] = pv;
                    rs += pv;
                }
            rs += __shfl_xor(rs, 16);
            rs += __shfl_xor(rs, 32);
            l_i += rs;

            // rescale oacc rows (row q = 4*lgp + i2; fe lives at lane with lr == that q)
            float feb[4];
#pragma unroll
            for (int i2 = 0; i2 < 4; ++i2) feb[i2] = __shfl(fe, 4 * lgp + i2);
#pragma unroll
            for (int t = 0; t < 8; ++t)
#pragma unroll
                for (int i2 = 0; i2 < 4; ++i2) oacc[t][i2] *= feb[i2];

            // P (A-operand, permuted-k): slot i<4 -> sc[2kk][i], slot i>=4 -> sc[2kk+1][i-4]
            short8 ap[2];
#pragma unroll
            for (int kk = 0; kk < 2; ++kk)
#pragma unroll
                for (int j = 0; j < 4; ++j) {
                    ap[kk][j]     = (short)f2bf(sc[2 * kk][j]);
                    ap[kk][4 + j] = (short)f2bf(sc[2 * kk + 1][j]);
                }

            // PV: B = V^T fragments from Vt with the SAME permuted-k convention
            __builtin_amdgcn_s_setprio(1);
#pragma unroll
            for (int t = 0; t < 8; ++t) {
                const int d = t * 16 + lr;
                const int swz = (d & 7) << 3;
                const int dbase = d * 64;
#pragma unroll
                for (int kk = 0; kk < 2; ++kk) {
                    short4v lo = *(const short4v*)&Vt[cur][(dbase + kk * 32 + lgp * 4) ^ swz];
                    short4v hi = *(const short4v*)&Vt[cur][(dbase + kk * 32 + 16 + lgp * 4) ^ swz];
                    short8 bv;
                    bv[0] = lo[0]; bv[1] = lo[1]; bv[2] = lo[2]; bv[3] = lo[3];
                    bv[4] = hi[0]; bv[5] = hi[1]; bv[6] = hi[2]; bv[7] = hi[3];
                    oacc[t] = __builtin_amdgcn_mfma_f32_16x16x32_bf16(ap[kk], bv, oacc[t], 0, 0, 0);
                }
            }
            __builtin_amdgcn_s_setprio(0);

            if (kb < qt) {
#pragma unroll
                for (int r2 = 0; r2 < 4; ++r2) vcur[r2] = vnext[r2];
            }
            cur ^= 1;
        }

        // epilogue: O[q][d], q = qt*64 + wv*16 + 4*lgp + i2, d = t*16 + lr
        float invb[4];
        {
            float inv = 1.0f / l_i;
#pragma unroll
            for (int i2 = 0; i2 < 4; ++i2) invb[i2] = __shfl(inv, 4 * lgp + i2);
        }
        float* ob = O + (size_t)(qt * 64 + wv * 16 + 4 * lgp) * HID + h * HDIM + lr;
#pragma unroll
        for (int t = 0; t < 8; ++t)
#pragma unroll
            for (int i2 = 0; i2 < 4; ++i2)
                ob[(size_t)i2 * HID + t * 16] = oacc[t][i2] * invb[i2];
    }
}

// ---------------- launch ----------------
extern "C" void kernel_launch(void* const* d_in, const int* in_sizes, int n_in,
                              void* d_out, int out_size, void* d_ws, size_t ws_size,
                              hipStream_t stream) {
    const float* hidden = (const float*)d_in[0];
    const int*   pos    = (const int*)d_in[1];
    const float* su_qkv = (const float*)d_in[2];
    const float* su_o   = (const float*)d_in[3];
    const float* ws_qkv = (const float*)d_in[4];
    const float* ws_o   = (const float*)d_in[5];
    const float* Wq     = (const float*)d_in[6];
    const float* Wk     = (const float*)d_in[7];
    const float* Wv     = (const float*)d_in[8];
    const float* Wo     = (const float*)d_in[9];
    float* out = (float*)d_out;

    char* ws = (char*)d_ws;
    unsigned short* Wcat = (unsigned short*)(ws);                        // [6144][4096] bf16
    unsigned short* Wob  = (unsigned short*)(ws + 50331648);             // [4096][4096] bf16
    unsigned short* xb   = (unsigned short*)(ws + 83886080);             // [2048][4096] bf16 (reused as y_in)
    float*          qkv  = (float*)(ws + 100663296);                     // [2048][6144] f32 (reused as attn_out)
    unsigned short* Qb   = (unsigned short*)(ws + 150994944);            // [32][2048][128] bf16
    unsigned short* Kb   = Qb + (size_t)NHEAD * S_LEN * HDIM;
    unsigned short* Vb   = Kb + (size_t)NKVH * S_LEN * HDIM;
    float* attn_out = qkv;

    cvt_kernel<<<1024, 256, 0, stream>>>(Wq, Wcat, HID * HID);
    cvt_kernel<<<256, 256, 0, stream>>>(Wk, Wcat + (size_t)HID * HID, NKVH * HDIM * HID);
    cvt_kernel<<<256, 256, 0, stream>>>(Wv, Wcat + (size_t)(HID + NKVH * HDIM) * HID, NKVH * HDIM * HID);
    cvt_kernel<<<1024, 256, 0, stream>>>(Wo, Wob, HID * HID);

    fwht_kernel<<<S_LEN, 256, 0, stream>>>(hidden, su_qkv, xb);
    gemm_bt<<<dim3(NQKV / 128, S_LEN / 128), 256, 0, stream>>>(xb, Wcat, ws_qkv, qkv, S_LEN, NQKV, HID);
    rope_kernel<<<S_LEN, 256, 0, stream>>>(qkv, pos, Qb, Kb, Vb);
    attn_kernel<<<dim3(16, NHEAD), 256, 0, stream>>>(Qb, Kb, Vb, attn_out);
    fwht_kernel<<<S_LEN, 256, 0, stream>>>(attn_out, su_o, xb);
    gemm_bt<<<dim3(HID / 128, S_LEN / 128), 256, 0, stream>>>(xb, Wob, ws_o, out, S_LEN, HID, HID);
}